// Round 11
// baseline (650.700 us; speedup 1.0000x reference)
//
#include <hip/hip_runtime.h>
#include <stdint.h>

#define NNODES 50000
#define NEDGES 400000
#define MPAD   50048   // 391 * 128 = 782 * 64
#define MTILES 391
#define ZRF    0.8f
#define GNEPS  1e-5f
#define NBLK   196     // ceil(NNODES/256)

typedef unsigned short u16;
typedef __bf16 bf16x8 __attribute__((ext_vector_type(8)));
typedef float  f32x4  __attribute__((ext_vector_type(4)));

// bf16 weight arena offsets (elements)
#define OFF_NODEW 0
#define OFF_NQM   32768
#define OFF_TCAT  163840
#define OFF_GAT   425984
#define OFF_CCAT  557056
#define W_TOTAL   1081344

__device__ __forceinline__ float b2f(u16 u){ union{uint32_t i; float f;} x; x.i=((uint32_t)u)<<16; return x.f; }
__device__ __forceinline__ u16 f2b(float f){ union{float f; uint32_t i;} x; x.f=f; uint32_t r=x.i+0x7FFFu+((x.i>>16)&1u); return (u16)(r>>16); }
__device__ __forceinline__ float lrelu(float x){ return x>0.f? x : 0.2f*x; }
__device__ __forceinline__ void atomicMaxF(float* a, float v){
  if (v>=0.f) atomicMax((int*)a, __float_as_int(v));
  else atomicMin((unsigned int*)a, (unsigned int)__float_as_int(v));
}

__device__ __forceinline__ void gl16(const void* g, void* l){
  __builtin_amdgcn_global_load_lds((const __attribute__((address_space(1))) void*)g,
                                   (__attribute__((address_space(3))) void*)l, 16, 0, 0);
}
__device__ __forceinline__ void bar(){
  __builtin_amdgcn_sched_barrier(0);
  asm volatile("" ::: "memory");
  __builtin_amdgcn_s_barrier();
  asm volatile("" ::: "memory");
  __builtin_amdgcn_sched_barrier(0);
}

// =================== FUSE3 v2: pipelined nqm -> tcat(mix) -> gat(+dotav) ===================
// 64-row strip per block; each wave owns 16 rows end-to-end (bufC is wave-private).
// B streamed in 64 chunks of 16 rows through 3 x 8KB buffers; stage c+2 after the single
// per-chunk barrier; counted vmcnt(2) (never 0 mid-loop) — r9 GEMM schedule.
__global__ __launch_bounds__(256, 2) void fuse3(
    const u16* __restrict__ X, const u16* __restrict__ Wn, const float* __restrict__ qb_,
    const u16* __restrict__ Wt, const float* __restrict__ bt,
    const u16* __restrict__ Wg,
    const float* __restrict__ asrc, const float* __restrict__ adst,
    const uint32_t* __restrict__ mask,
    u16* __restrict__ xc, u16* __restrict__ xw,
    float* __restrict__ avs, float* __restrict__ avd)
{
  __shared__ alignas(16) u16 bufS[3*4096];   // 3 x 8KB B-staging
  __shared__ alignas(16) u16 bufC[16384];    // 32KB x/xc/h strip (wave-private rows)
  __shared__ float wam[64];

  const int tid  = threadIdx.x;
  const int lane = tid & 63, wv = tid >> 6;
  const int lrow = lane & 15;
  const int kq   = lane >> 4;

  const int nwg = gridDim.x;
  const int qc = nwg >> 3, rc = nwg & 7;
  const int xcd = blockIdx.x & 7, xi = blockIdx.x >> 3;
  const int lt = (xcd < rc ? xcd*(qc+1) : rc*(qc+1) + (xcd-rc)*qc) + xi;
  const int bm0 = lt * 64;

  const int rloc = (wv << 4) + lrow;        // this lane's A-row (local 0..63)

  // physical-linear LDS, swizzle on global source + read side (rule #21)
#define CADDR(kt, r, q) ((char*)bufC + (kt)*4096 + (r)*64 + (((q) ^ (((r)>>1)&3))<<4))
#define SADDR(sb, kt, r, q) ((char*)bufS + (sb)*8192 + (kt)*1024 + (r)*64 + (((q) ^ (((r)>>1)&3))<<4))

  // ---- prologue: stage own x rows -> bufC (wave-private; no barrier needed) ----
  {
    int row = tid >> 2, g = tid & 3, sw = (row >> 1) & 3;
#pragma unroll
    for (int j = 0; j < 8; ++j)
      gl16(X + (size_t)(bm0 + row)*256 + j*32 + ((g ^ sw)<<3),
           (char*)bufC + j*4096 + tid*16);
  }
  if (tid < 64) {
    int gr = bm0 + tid;
    wam[tid] = (gr < NNODES && mask[gr]) ? ZRF : (1.0f - ZRF);
  }
  asm volatile("s_waitcnt vmcnt(0)" ::: "memory");
  bf16x8 af[8];
#pragma unroll
  for (int kt = 0; kt < 8; ++kt)
    af[kt] = *(const bf16x8*)CADDR(kt, rloc, kq);

  // chunk gc -> (W pointer, row base). 0-15: Wn; 16-47: Wt (even=t1,odd=t0); 48-63: Wg.
  auto stageC = [&](int gc, int sb){
    const u16* Wp; int rowbase;
    if (gc < 16)      { Wp = Wn; rowbase = gc*16; }
    else if (gc < 48) { int i = gc-16; Wp = Wt + (size_t)(i&1)*65536; rowbase = (i>>1)*16; }
    else              { Wp = Wg; rowbase = (gc-48)*16; }
    int row = (lane >> 2), g = lane & 3, sw = (row >> 1) & 3;
#pragma unroll
    for (int j = 0; j < 2; ++j) {
      int kt = j*4 + wv;
      gl16(Wp + (size_t)(rowbase + row)*256 + kt*32 + ((g ^ sw)<<3),
           (char*)bufS + sb*8192 + j*4096 + tid*16);
    }
  };

  // WFRAG: write one D-frag (4 rows of this wave) into bufC at column col
#define WFRAG(col, v0_, v1_, v2_, v3_) do { \
    int kt_ = (col) >> 5, cc_ = (col) & 31, g_ = cc_ >> 3, pos_ = cc_ & 7; \
    float vv_[4] = { v0_, v1_, v2_, v3_ }; \
    _Pragma("unroll") for (int r_ = 0; r_ < 4; ++r_) { \
      int rd_ = (wv<<4) + (kq<<2) + r_; \
      *(u16*)(CADDR(kt_, rd_, g_) + pos_*2) = f2b(vv_[r_]); } } while (0)

  stageC(0, 0);
  stageC(1, 1);

  f32x4 p1hold = {};
  float sp[4] = {0,0,0,0}, dp[4] = {0,0,0,0};

  for (int gc = 0; gc < 64; ++gc) {
    if (gc < 63) { asm volatile("s_waitcnt vmcnt(2)" ::: "memory"); }
    else         { asm volatile("s_waitcnt vmcnt(0)" ::: "memory"); }
    bar();                                  // chunk gc visible; all waves past chunk gc-1
    if (gc + 2 < 64) stageC(gc + 2, (gc + 2) % 3);
    const int sb = gc % 3;

    f32x4 a = {};
#pragma unroll
    for (int kt = 0; kt < 8; ++kt) {
      bf16x8 bv = *(const bf16x8*)SADDR(sb, kt, lrow, kq);
      a = __builtin_amdgcn_mfma_f32_16x16x32_bf16(af[kt], bv, a, 0, 0, 0);
    }

    if (gc < 16) {
      // step 1: xc = relu(x @ Wn^T + qb)
      int col = gc*16 + lrow;
      float bb = qb_[col];
      WFRAG(col, fmaxf(a[0]+bb,0.f), fmaxf(a[1]+bb,0.f), fmaxf(a[2]+bb,0.f), fmaxf(a[3]+bb,0.f));
      if (gc == 15) {
        // af <- xc (own rows); xc writeback (own rows)
#pragma unroll
        for (int kt = 0; kt < 8; ++kt)
          af[kt] = *(const bf16x8*)CADDR(kt, rloc, kq);
        int row = tid >> 2, g = tid & 3;
#pragma unroll
        for (int kt = 0; kt < 8; ++kt) {
          uint4 v = *(const uint4*)CADDR(kt, row, g);
          *(uint4*)&xc[(size_t)(bm0 + row)*256 + kt*32 + g*8] = v;
        }
      }
    } else if (gc < 48) {
      // step 2: dual chunks (even=t1 frag, odd=t0 frag) -> mix -> h
      int i = gc - 16;
      if (!(i & 1)) { p1hold = a; }
      else {
        int p = i >> 1;
        int col = p*16 + lrow;
        float b1v = bt[col], b0v = bt[256 + col];
        int kt_ = col >> 5, cc_ = col & 31, g_ = cc_ >> 3, pos_ = cc_ & 7;
#pragma unroll
        for (int r_ = 0; r_ < 4; ++r_) {
          int rd_ = (wv<<4) + (kq<<2) + r_;
          float wa = wam[rd_];
          float hv = wa * fmaxf(p1hold[r_] + b1v, 0.f) + (1.0f - wa) * fmaxf(a[r_] + b0v, 0.f);
          *(u16*)(CADDR(kt_, rd_, g_) + pos_*2) = f2b(hv);
        }
        if (gc == 47) {
#pragma unroll
          for (int kt = 0; kt < 8; ++kt)
            af[kt] = *(const bf16x8*)CADDR(kt, rloc, kq);
        }
      }
    } else {
      // step 3: xw = h @ Wg^T + dotav partials
      int col = (gc-48)*16 + lrow;
      float as_ = asrc[col], ad_ = adst[col];
#pragma unroll
      for (int r_ = 0; r_ < 4; ++r_) { sp[r_] += a[r_]*as_; dp[r_] += a[r_]*ad_; }
      WFRAG(col, a[0], a[1], a[2], a[3]);
    }
  }

  // dotav reduce over the 16 lrow lanes; rows unique per (wv,kq,r) -> plain store
#pragma unroll
  for (int r_ = 0; r_ < 4; ++r_) {
    float s_ = sp[r_], d_ = dp[r_];
    s_ += __shfl_xor(s_, 1); s_ += __shfl_xor(s_, 2); s_ += __shfl_xor(s_, 4); s_ += __shfl_xor(s_, 8);
    d_ += __shfl_xor(d_, 1); d_ += __shfl_xor(d_, 2); d_ += __shfl_xor(d_, 4); d_ += __shfl_xor(d_, 8);
    if (lrow == 0) {
      int row = bm0 + (wv<<4) + (kq<<2) + r_;
      avs[row] = s_;
      avd[row] = d_;
    }
  }
  // xw writeback (own rows)
  {
    int row = tid >> 2, g = tid & 3;
#pragma unroll
    for (int kt = 0; kt < 8; ++kt) {
      uint4 v = *(const uint4*)CADDR(kt, row, g);
      *(uint4*)&xw[(size_t)(bm0 + row)*256 + kt*32 + g*8] = v;
    }
  }
#undef CADDR
#undef SADDR
#undef WFRAG
}

// ---------------- bf16 MFMA GEMM body (g_nin, g_ccat) — unchanged r9 pipeline ----------------
template<int DUAL,int SPLIT,int RELU,int STATS>
__device__ __forceinline__ void gemm_body(const u16* __restrict__ A0, const u16* __restrict__ A1,
    int ldA, const u16* __restrict__ B, const float* __restrict__ bias,
    u16* __restrict__ out, int ldo, int NT, int K,
    const uint32_t* __restrict__ mask, float* __restrict__ sums)
{
  __shared__ alignas(16) char smem[50176];
  char* sm = smem;
  float* was = (float*)(smem + 49152);
  float* val = was + 128;

  const int tid  = threadIdx.x;
  const int nwg = gridDim.x;
  const int qc = nwg >> 3, rc = nwg & 7;
  const int xcd = blockIdx.x & 7, xi = blockIdx.x >> 3;
  const int lt = (xcd < rc ? xcd * (qc + 1) : rc * (qc + 1) + (xcd - rc) * qc) + xi;
  const int bm0 = (lt / NT) * 128;
  const int bn0 = (lt % NT) * (DUAL ? 64 : 128);

  if (DUAL && tid < 128) {
    int gr = bm0 + tid;
    int mk = (gr < NNODES) ? (mask[gr] != 0) : 0;
    was[tid] = mk ? ZRF : (1.0f - ZRF);
    val[tid] = (gr < NNODES) ? 1.0f : 0.0f;
  }

  const int lane = tid & 63;
  const int wv   = tid >> 6;
  const int wm   = (wv >> 1) * 64;
  const int wn   = (wv & 1) * (DUAL ? 32 : 64);
  const int lrow = lane & 15;
  const int kg16 = (lane >> 4) * 16;
  const int swz  = ((lrow >> 1) & 3) << 4;

  const int rA  = ((wv << 6) + lane) >> 2;
  const int gsw = (((lane & 3) ^ ((rA >> 1) & 3)) << 3);
  const u16* pa  = A0 + (size_t)(bm0 + rA) * ldA + gsw;
  const u16* pa2 = pa + 64 * ldA;
  const u16* pa1  = SPLIT ? (A1 + (size_t)(bm0 + rA) * 256 + gsw) : nullptr;
  const u16* pa12 = SPLIT ? (pa1 + 64 * 256) : nullptr;
  const u16* pb0 = B + (size_t)(bn0 + rA) * K + gsw;
  const u16* pb1 = DUAL ? (B + (size_t)(256 + bn0 + rA) * K + gsw) : (pb0 + (size_t)64 * K);
  const int dA0 = wv * 1024, dA1 = 4096 + wv * 1024;
  const int dB0 = 8192 + wv * 1024, dB1 = 12288 + wv * 1024;

  const int KT = K >> 5;
  f32x4 acc[DUAL ? 2 : 1][4][DUAL ? 2 : 4] = {};

#define STAGE(off, ktv) do { \
    int ks_ = (ktv) * 32; \
    const u16 *qa_, *qa2_; \
    if (SPLIT && ks_ >= 256) { qa_ = pa1 + (ks_ - 256); qa2_ = pa12 + (ks_ - 256); } \
    else                     { qa_ = pa + ks_;           qa2_ = pa2 + ks_; } \
    char* db_ = sm + (off); \
    gl16(qa_,       db_ + dA0); \
    gl16(qa2_,      db_ + dA1); \
    gl16(pb0 + ks_, db_ + dB0); \
    gl16(pb1 + ks_, db_ + dB1); \
  } while (0)

  STAGE(0, 0);
  if (KT > 1) STAGE(16384, 1);
  int rd = 0;
  for (int kt = 0; kt < KT; ++kt) {
    if (kt + 1 < KT) { asm volatile("s_waitcnt vmcnt(4)" ::: "memory"); }
    else             { asm volatile("s_waitcnt vmcnt(0)" ::: "memory"); }
    bar();
    if (kt + 2 < KT) { int st = rd >= 1 ? rd - 1 : 2; STAGE(st * 16384, kt + 2); }
    const char* Ab = sm + rd * 16384;
    const char* Bb = Ab + 8192;
    bf16x8 af[4];
#pragma unroll
    for (int mi = 0; mi < 4; ++mi)
      af[mi] = *(const bf16x8*)(Ab + (wm + mi * 16 + lrow) * 64 + (kg16 ^ swz));
    if (DUAL) {
#pragma unroll
      for (int ni = 0; ni < 2; ++ni) {
        int ro = (wn + ni * 16 + lrow) * 64 + (kg16 ^ swz);
        bf16x8 b0 = *(const bf16x8*)(Bb + ro);
        bf16x8 b1 = *(const bf16x8*)(Bb + 4096 + ro);
#pragma unroll
        for (int mi = 0; mi < 4; ++mi) {
          acc[0][mi][ni] = __builtin_amdgcn_mfma_f32_16x16x32_bf16(af[mi], b0, acc[0][mi][ni], 0, 0, 0);
          acc[DUAL?1:0][mi][ni] = __builtin_amdgcn_mfma_f32_16x16x32_bf16(af[mi], b1, acc[DUAL?1:0][mi][ni], 0, 0, 0);
        }
      }
    } else {
#pragma unroll
      for (int ni = 0; ni < (DUAL ? 2 : 4); ++ni) {
        bf16x8 bv = *(const bf16x8*)(Bb + (wn + ni * 16 + lrow) * 64 + (kg16 ^ swz));
#pragma unroll
        for (int mi = 0; mi < 4; ++mi)
          acc[0][mi][ni] = __builtin_amdgcn_mfma_f32_16x16x32_bf16(af[mi], bv, acc[0][mi][ni], 0, 0, 0);
      }
    }
    rd = (rd + 1 == 3) ? 0 : rd + 1;
  }
#undef STAGE
  bar();

  const int rb = (lane >> 4) * 4;   // D: col = lane&15, row = (lane>>4)*4 + reg
  u16* ep = (u16*)smem;
  if (DUAL) {
    float sA[2] = {0, 0}, qA[2] = {0, 0};
#pragma unroll
    for (int ni = 0; ni < 2; ++ni) {
      int coll = wn + ni * 16 + lrow;
      float b1v = bias[bn0 + coll];
      float b0v = bias[256 + bn0 + coll];
#pragma unroll
      for (int mi = 0; mi < 4; ++mi) {
        int rowl = wm + mi * 16 + rb;
#pragma unroll
        for (int r = 0; r < 4; ++r) {
          float v1 = acc[0][mi][ni][r] + b1v;
          float v0 = acc[DUAL?1:0][mi][ni][r] + b0v;
          if (RELU) { v1 = fmaxf(v1, 0.f); v0 = fmaxf(v0, 0.f); }
          float wa = was[rowl + r];
          float v = wa * v1 + (1.0f - wa) * v0;
          if (STATS) { float vl = val[rowl + r]; sA[ni] += v * vl; qA[ni] += v * v * vl; }
          ep[(rowl + r) * 72 + coll] = f2b(v);
        }
      }
    }
    bar();
#pragma unroll
    for (int p = 0; p < 4; ++p) {
      int rowl = p * 32 + (tid >> 3);
      uint4 v = *(const uint4*)&ep[rowl * 72 + (tid & 7) * 8];
      *(uint4*)&out[(size_t)(bm0 + rowl) * ldo + bn0 + (tid & 7) * 8] = v;
    }
    if (STATS) {
#pragma unroll
      for (int ni = 0; ni < 2; ++ni) {
        sA[ni] += __shfl_xor(sA[ni], 16); sA[ni] += __shfl_xor(sA[ni], 32);
        qA[ni] += __shfl_xor(qA[ni], 16); qA[ni] += __shfl_xor(qA[ni], 32);
      }
      if (lane < 16) {
#pragma unroll
        for (int ni = 0; ni < 2; ++ni) {
          int gc = bn0 + wn + ni * 16 + lane;
          atomicAdd(&sums[gc], sA[ni]);
          atomicAdd(&sums[256 + gc], qA[ni]);
        }
      }
    }
  } else {
#pragma unroll
    for (int ni = 0; ni < 4; ++ni) {
      int coll = wn + ni * 16 + lrow;
      float bv = bias ? bias[bn0 + coll] : 0.f;
#pragma unroll
      for (int mi = 0; mi < 4; ++mi) {
        int rowl = wm + mi * 16 + rb;
#pragma unroll
        for (int r = 0; r < 4; ++r) {
          float v = acc[0][mi][ni][r] + bv;
          if (RELU) v = fmaxf(v, 0.f);
          ep[(rowl + r) * 132 + coll] = f2b(v);
        }
      }
    }
    bar();
#pragma unroll
    for (int p = 0; p < 8; ++p) {
      int rowl = p * 16 + (tid >> 4);
      uint4 v = *(const uint4*)&ep[rowl * 132 + (tid & 15) * 8];
      *(uint4*)&out[(size_t)(bm0 + rowl) * ldo + bn0 + (tid & 15) * 8] = v;
    }
  }
}

__global__ __launch_bounds__(256, 3) void g_nin(const u16* __restrict__ A, const u16* __restrict__ W,
    const float* __restrict__ b, u16* __restrict__ o)
{ gemm_body<0,0,1,0>(A, nullptr, 128, W, b, o, 256, 2, 128, nullptr, nullptr); }

__global__ __launch_bounds__(256, 3) void g_ccat(const u16* __restrict__ A0, const u16* __restrict__ A1,
    const u16* __restrict__ W, const float* __restrict__ b, u16* __restrict__ o,
    const uint32_t* __restrict__ mask, float* __restrict__ sums)
{ gemm_body<1,1,0,1>(A0, A1, 256, W, b, o, 256, 4, 512, mask, sums); }

// ---------------- weight fold with inline graph-norm scale/shift ----------------
__global__ void foldw(const u16* __restrict__ Ws, const float* __restrict__ bs,
                      const float* __restrict__ sums, const float* __restrict__ w,
                      const float* __restrict__ b, const float* __restrict__ a,
                      int K, u16* __restrict__ Wd, float* __restrict__ bd){
  __shared__ float scs[256], shs[256];
  int n = blockIdx.x, t = threadIdx.x;
  {
    const float invn = 1.0f / (float)NNODES;
    float mu  = sums[t] * invn;
    float ex2 = sums[256 + t] * invn;
    float av  = a[t];
    float var = ex2 - (2.0f*av - av*av)*mu*mu;
    float sc  = w[t] / sqrtf(var + GNEPS);
    scs[t] = sc;
    shs[t] = b[t] - sc*av*mu;
  }
  __syncthreads();
  float bacc = 0.f;
  for (int k = t; k < K; k += 256) {
    float wv = b2f(Ws[(size_t)n * K + k]);
    if (k < 256) { bacc += wv * shs[k]; wv *= scs[k]; }
    Wd[(size_t)n * K + k] = f2b(wv);
  }
  for (int d = 32; d; d >>= 1) bacc += __shfl_xor(bacc, d);
  __shared__ float red[4];
  if ((t & 63) == 0) red[t >> 6] = bacc;
  __syncthreads();
  if (t == 0) bd[n] = bs[n] + red[0] + red[1] + red[2] + red[3];
}

// ---------------- merged setup kernel: zeroall | convw | convxin | biascat | qk | detmask ----------------
#define S0 256
#define S1 (S0 + 4224)
#define S2 (S1 + 6256)
#define S3 (S2 + 8)
#define S4 (S3 + 1)
#define S5 (S4 + NBLK)
__global__ void setup1(
    float* __restrict__ zar, int ztot, float* __restrict__ pmax,
    const float* __restrict__ nodeW, const float* __restrict__ nqmW,
    const float* __restrict__ t0W, const float* __restrict__ t1W,
    const float* __restrict__ gatW, const float* __restrict__ c0W,
    const float* __restrict__ c1W, u16* __restrict__ arena,
    const float* __restrict__ x, u16* __restrict__ xin,
    const float* __restrict__ t1b, const float* __restrict__ t0b,
    const float* __restrict__ c1b, const float* __restrict__ c0b,
    float* __restrict__ tb, float* __restrict__ cb,
    const float* __restrict__ qemb, const float* __restrict__ qinW,
    const float* __restrict__ qinB, const float* __restrict__ nqmB,
    float* __restrict__ qb,
    const unsigned char* __restrict__ mb, int* __restrict__ mcnt)
{
  int b = blockIdx.x, t = threadIdx.x;
  if (b < S0) {
    int i = b*256 + t;
    if (i < 256) pmax[i] = -__builtin_inff();
    for (int j = i; j < ztot; j += S0*256) zar[j] = 0.f;
  } else if (b < S1) {
    int idx = (b - S0)*256 + t;
    if (idx >= W_TOTAL) return;
    float v;
    if (idx < OFF_NQM) { v = nodeW[idx]; }
    else if (idx < OFF_TCAT){ int i = idx - OFF_NQM;  int l=i>>16; int r=(i>>8)&255; int k=i&255; v = nqmW[l*131072 + r*512 + k]; }
    else if (idx < OFF_GAT) { int i = idx - OFF_TCAT; int l=i>>17; int n=(i>>8)&511; int k=i&255;
                              const float* s = (n<256)? t1W : t0W; v = s[l*65536 + (n&255)*256 + k]; }
    else if (idx < OFF_CCAT){ int i = idx - OFF_GAT;  v = gatW[i]; }
    else                    { int i = idx - OFF_CCAT; int l=i>>18; int n=(i>>9)&511; int k=i&511;
                              const float* s = (n<256)? c1W : c0W; v = s[l*131072 + (n&255)*512 + k]; }
    arena[idx] = f2b(v);
  } else if (b < S2) {
    int idx = (b - S1)*256 + t;
    if (idx >= MPAD*32) return;
    int n = idx >> 5; int c = (idx & 31)*4;
    float4 v = make_float4(0.f,0.f,0.f,0.f);
    if (n < NNODES) v = *(const float4*)&x[(size_t)n*128 + c];
    ushort4 r; r.x=f2b(v.x); r.y=f2b(v.y); r.z=f2b(v.z); r.w=f2b(v.w);
    *(ushort4*)&xin[(size_t)n*128 + c] = r;
  } else if (b < S3) {
    int i = (b - S2)*256 + t;
    if (i >= 2048) return;
    int which = i >> 10; int j = i & 1023; int l = j >> 9; int n = j & 511;
    const float* b1 = which ? c1b : t1b;
    const float* b0 = which ? c0b : t0b;
    float v = (n < 256) ? b1[l*256 + n] : b0[l*256 + n - 256];
    (which ? cb : tb)[l*512 + n] = v;
  } else if (b < S4) {
    __shared__ float qvs[256];
    float a = qinB[t];
    for (int d = 0; d < 128; ++d) a += qemb[d] * qinW[t*128 + d];
    qvs[t] = fmaxf(a, 0.f);
    __syncthreads();
    for (int l = 0; l < 2; ++l) {
      const float* wr = nqmW + l*131072 + t*512 + 256;
      float acc = nqmB[l*256 + t];
      for (int j = 0; j < 256; ++j) acc += wr[j] * qvs[j];
      qb[l*256 + t] = acc;
    }
  } else {
    int i = (b - S4)*256 + t;
    int c = (i < NNODES) ? (mb[i] != 0) : 0;
    for (int d = 32; d; d >>= 1) c += __shfl_xor(c, d);
    __shared__ int red[4];
    if ((t & 63) == 0) red[t >> 6] = c;
    __syncthreads();
    if (t == 0) atomicAdd(mcnt, red[0] + red[1] + red[2] + red[3]);
  }
}

// ---------------- merged maskmat + hist ----------------
__global__ void mh(const void* __restrict__ mraw, const int* __restrict__ mcnt,
                   uint32_t* __restrict__ mask,
                   const int* __restrict__ dst, int* __restrict__ count){
  int b = blockIdx.x, t = threadIdx.x;
  if (b < NBLK) {
    int i = b*256 + t;
    if (i >= NNODES) return;
    int f = ((*mcnt) * 8 > NNODES * 3);
    mask[i] = f ? (((const unsigned char*)mraw)[i] != 0) : (((const int*)mraw)[i] != 0);
  } else {
    int i = (b - NBLK)*256 + t;
    if (i < NEDGES) atomicAdd(&count[dst[i]], 1);
  }
}

// ---------------- scan chain ----------------
__global__ void bsum(const int* __restrict__ count, int* __restrict__ bsums){
  int b = blockIdx.x, t = threadIdx.x;
  int i = b * 256 + t;
  int v = (i < NNODES) ? count[i] : 0;
  for (int d = 32; d; d >>= 1) v += __shfl_xor(v, d);
  __shared__ int red[4];
  if ((t & 63) == 0) red[t >> 6] = v;
  __syncthreads();
  if (t == 0) bsums[b] = red[0] + red[1] + red[2] + red[3];
}

__global__ void bscan(const int* __restrict__ bsums, int* __restrict__ bpre){
  int t = threadIdx.x;
  int v = (t < NBLK) ? bsums[t] : 0;
  __shared__ int tmp[256];
  tmp[t] = v;
  __syncthreads();
  for (int d = 1; d < 256; d <<= 1) {
    int add = (t >= d) ? tmp[t - d] : 0;
    __syncthreads();
    tmp[t] += add;
    __syncthreads();
  }
  if (t < NBLK) bpre[t] = tmp[t] - v;
}

__global__ void scanblk(const int* __restrict__ count, const int* __restrict__ bpre,
                        int* __restrict__ offs, int* __restrict__ cursor){
  int b = blockIdx.x, t = threadIdx.x;
  int i = b * 256 + t;
  int v = (i < NNODES) ? count[i] : 0;
  __shared__ int tmp[256];
  tmp[t] = v;
  __syncthreads();
  for (int d = 1; d < 256; d <<= 1) {
    int add = (t >= d) ? tmp[t - d] : 0;
    __syncthreads();
    tmp[t] += add;
    __syncthreads();
  }
  int excl = bpre[b] + tmp[t] - v;
  if (i < NNODES) { offs[i] = excl; cursor[i] = excl; }
  if (i == NNODES - 1) offs[NNODES] = excl + v;
}

__global__ void scatter(const int* __restrict__ src, const int* __restrict__ dst,
                        int* __restrict__ cursor, int* __restrict__ ssrc){
  int i = blockIdx.x*256 + threadIdx.x;
  if (i >= NEDGES) return;
  int p = atomicAdd(&cursor[dst[i]], 1);
  ssrc[p] = src[i];
}

// ---------------- graph kernels ----------------
__global__ void agg(const int* __restrict__ offs, const int* __restrict__ ssrc,
                    const float* __restrict__ avs, const float* __restrict__ avd,
                    const u16* __restrict__ xw, const float* __restrict__ gbias,
                    u16* __restrict__ out){
  int v = (blockIdx.x*256 + threadIdx.x) >> 6;
  int lane = threadIdx.x & 63;
  if (v >= NNODES) return;
  int o0 = offs[v], o1 = offs[v+1];
  int deg = o1 - o0;
  float ad = avd[v];
  float slog = lrelu(avs[v] + ad);
  int c = lane*4;
  ushort4 xv = *(const ushort4*)&xw[(size_t)v*256 + c];
  float a0, a1, a2, a3;
  if (deg <= 64) {
    int s = 0; float logit = -3.0e38f;
    if (lane < deg) { s = ssrc[o0 + lane]; logit = lrelu(avs[s] + ad); }
    float m = fmaxf(slog, logit);
    for (int d = 32; d; d >>= 1) m = fmaxf(m, __shfl_xor(m, d));
    float w = (lane < deg) ? __expf(logit - m) : 0.f;
    float den = w + ((lane == 0) ? __expf(slog - m) : 0.f);
    for (int d = 32; d; d >>= 1) den += __shfl_xor(den, d);
    float rden = 1.0f / (den + 1e-16f);
    w *= rden;
    float wgt = __expf(slog - m) * rden;
    a0 = wgt*b2f(xv.x); a1 = wgt*b2f(xv.y); a2 = wgt*b2f(xv.z); a3 = wgt*b2f(xv.w);
    int i = 0;
    for (; i + 8 <= deg; i += 8) {
      ushort4 q[8]; float ww[8];
#pragma unroll
      for (int j = 0; j < 8; ++j) {
        int sj = __shfl(s, i + j); ww[j] = __shfl(w, i + j);
        q[j] = *(const ushort4*)&xw[(size_t)sj*256 + c];
      }
#pragma unroll
      for (int j = 0; j < 8; ++j) {
        a0 += ww[j]*b2f(q[j].x); a1 += ww[j]*b2f(q[j].y);
        a2 += ww[j]*b2f(q[j].z); a3 += ww[j]*b2f(q[j].w);
      }
    }
    for (; i + 4 <= deg; i += 4) {
      ushort4 q[4]; float ww[4];
#pragma unroll
      for (int j = 0; j < 4; ++j) {
        int sj = __shfl(s, i + j); ww[j] = __shfl(w, i + j);
        q[j] = *(const ushort4*)&xw[(size_t)sj*256 + c];
      }
#pragma unroll
      for (int j = 0; j < 4; ++j) {
        a0 += ww[j]*b2f(q[j].x); a1 += ww[j]*b2f(q[j].y);
        a2 += ww[j]*b2f(q[j].z); a3 += ww[j]*b2f(q[j].w);
      }
    }
    for (; i < deg; ++i) {
      int si = __shfl(s, i); float wi = __shfl(w, i);
      ushort4 q = *(const ushort4*)&xw[(size_t)si*256 + c];
      a0 += wi*b2f(q.x); a1 += wi*b2f(q.y); a2 += wi*b2f(q.z); a3 += wi*b2f(q.w);
    }
  } else {
    float m = slog;
    for (int i = o0 + lane; i < o1; i += 64) m = fmaxf(m, lrelu(avs[ssrc[i]] + ad));
    for (int d = 32; d; d >>= 1) m = fmaxf(m, __shfl_xor(m, d));
    float den = (lane == 0) ? __expf(slog - m) : 0.f;
    for (int i = o0 + lane; i < o1; i += 64) den += __expf(lrelu(avs[ssrc[i]] + ad) - m);
    for (int d = 32; d; d >>= 1) den += __shfl_xor(den, d);
    float rden = 1.0f / (den + 1e-16f);
    float wgt = __expf(slog - m) * rden;
    a0 = wgt*b2f(xv.x); a1 = wgt*b2f(xv.y); a2 = wgt*b2f(xv.z); a3 = wgt*b2f(xv.w);
    for (int i = o0; i < o1; ++i) {
      int si = ssrc[i];
      float wi = __expf(lrelu(avs[si] + ad) - m) * rden;
      ushort4 q = *(const ushort4*)&xw[(size_t)si*256 + c];
      a0 += wi*b2f(q.x); a1 += wi*b2f(q.y); a2 += wi*b2f(q.z); a3 += wi*b2f(q.w);
    }
  }
  float4 bb = *(const float4*)&gbias[c];
  ushort4 r;
  r.x = f2b(a0 + bb.x); r.y = f2b(a1 + bb.y); r.z = f2b(a2 + bb.z); r.w = f2b(a3 + bb.w);
  *(ushort4*)&out[(size_t)v*256 + c] = r;
}

__global__ void colstats(const u16* __restrict__ x, float* __restrict__ sums){
  int c = threadIdx.x;
  float s = 0.f, q = 0.f;
  for (int n = blockIdx.x; n < NNODES; n += gridDim.x){
    float v = b2f(x[(size_t)n*256 + c]); s += v; q += v*v;
  }
  atomicAdd(&sums[c], s); atomicAdd(&sums[256 + c], q);
}

__global__ void pool(const u16* __restrict__ x, const uint32_t* __restrict__ mask,
                     const float* __restrict__ sums, const float* __restrict__ w,
                     const float* __restrict__ b, const float* __restrict__ a,
                     float* __restrict__ psum, float* __restrict__ pmax, int* __restrict__ pcnt){
  int c = threadIdx.x;
  const float invn = 1.0f / (float)NNODES;
  float mu  = sums[c] * invn;
  float ex2 = sums[256 + c] * invn;
  float av  = a[c];
  float var = ex2 - (2.0f*av - av*av)*mu*mu;
  float sc  = w[c] / sqrtf(var + GNEPS);
  float sh  = b[c] - sc*av*mu;
  float s = 0.f, mx = -__builtin_inff(); int cnt = 0;
  for (int n = blockIdx.x; n < NNODES; n += gridDim.x){
    if (mask[n]){
      float v = b2f(x[(size_t)n*256 + c]) * sc + sh;
      s += v; mx = fmaxf(mx, v); cnt++;
    }
  }
  atomicAdd(&psum[c], s);
  atomicMaxF(&pmax[c], mx);
  if (c == 0) atomicAdd(pcnt, cnt);
}

__global__ void finalk(const float* __restrict__ psum, const float* __restrict__ pmax,
                       const int* __restrict__ pcnt, const float* __restrict__ W,
                       const float* __restrict__ b, float* __restrict__ out){
  int o = threadIdx.x;
  float cnt = fmaxf((float)(*pcnt), 1.0f);
  float inv = 1.0f / cnt;
  const float* wr = W + o*768;
  float acc = b[o];
  for (int j = 0; j < 256; ++j) acc += (psum[j]*inv) * wr[j];
  for (int j = 0; j < 256; ++j) acc += pmax[j] * wr[256 + j];
  for (int j = 0; j < 256; ++j) acc += psum[j] * wr[512 + j];
  out[o] = acc;
}

// ---------------- host orchestration ----------------
extern "C" void kernel_launch(void* const* d_in, const int* in_sizes, int n_in,
                              void* d_out, int out_size, void* d_ws, size_t ws_size,
                              hipStream_t stream)
{
  (void)in_sizes; (void)n_in; (void)out_size; (void)ws_size;
  const float* x_    = (const float*)d_in[0];
  const int*   eidx  = (const int*)  d_in[1];
  const float* qemb  = (const float*)d_in[3];
  const void*  mraw  =               d_in[4];
  const float* nodeW = (const float*)d_in[5];
  const float* nodeB = (const float*)d_in[6];
  const float* qinW  = (const float*)d_in[9];
  const float* qinB  = (const float*)d_in[10];
  const float* nqmW  = (const float*)d_in[11];
  const float* nqmB  = (const float*)d_in[12];
  const float* t0W   = (const float*)d_in[15];
  const float* t0B   = (const float*)d_in[16];
  const float* t1W   = (const float*)d_in[17];
  const float* t1B   = (const float*)d_in[18];
  const float* gatW  = (const float*)d_in[19];
  const float* gatAs = (const float*)d_in[20];
  const float* gatAd = (const float*)d_in[21];
  const float* gatB  = (const float*)d_in[22];
  const float* cgnW  = (const float*)d_in[23];
  const float* cgnB  = (const float*)d_in[24];
  const float* cgnA  = (const float*)d_in[25];
  const float* c0W   = (const float*)d_in[26];
  const float* c0B   = (const float*)d_in[27];
  const float* c1W   = (const float*)d_in[28];
  const float* c1B   = (const float*)d_in[29];
  const float* gnW   = (const float*)d_in[30];
  const float* gnB   = (const float*)d_in[31];
  const float* gnA   = (const float*)d_in[32];
  const float* finW  = (const float*)d_in[33];
  const float* finB  = (const float*)d_in[34];
  float* outp = (float*)d_out;

  char* p = (char*)d_ws;
  auto alloc = [&](size_t b)->char*{ char* r = p; p += (b + 511) & ~(size_t)511; return r; };
  u16*      arena = (u16*)     alloc((size_t)W_TOTAL*2);
  u16*      wtc   = (u16*)     alloc((size_t)512*512*2);
  u16*      wtn   = (u16*)     alloc((size_t)256*256*2);
  float*    btc   = (float*)   alloc(512*4);
  float*    qbt   = (float*)   alloc(256*4);
  float*    tb    = (float*)   alloc(1024*4);
  float*    cb    = (float*)   alloc(1024*4);
  float*    qb    = (float*)   alloc(512*4);
  float*    pmax  = (float*)   alloc(256*4);
  uint32_t* mask  = (uint32_t*)alloc((size_t)NNODES*4);
  int*      offs  = (int*)     alloc((size_t)(NNODES+1)*4);
  int*      cursor= (int*)     alloc((size_t)NNODES*4);
  int*      ssrc  = (int*)     alloc((size_t)NEDGES*4);
  int*      bsums = (int*)     alloc((size_t)NBLK*4);
  int*      bpre  = (int*)     alloc((size_t)NBLK*4);

  // zero arena: count | sumsC0 sumsC1 sumsG0 sumsG1 | av(4*MPAD) | psum | pcnt | mcnt
  const int Z_SUMS  = 50048;
  const int Z_AV    = Z_SUMS + 2048;
  const int Z_PSUM  = Z_AV + 4*MPAD;
  const int Z_PCNT  = Z_PSUM + 256;
  const int Z_MCNT  = Z_PCNT + 64;
  const int ZTOT    = Z_MCNT + 64;
  float*    zar   = (float*)   alloc((size_t)ZTOT*4);
  int*      count = (int*)zar;
  float*    sumsC0= zar + Z_SUMS;
  float*    sumsC1= zar + Z_SUMS + 512;
  float*    sumsG0= zar + Z_SUMS + 1024;
  float*    sumsG1= zar + Z_SUMS + 1536;
  float*    av    = zar + Z_AV;
  float*    psum  = zar + Z_PSUM;
  int*      pcnt  = (int*)(zar + Z_PCNT);
  int*      mcnt  = (int*)(zar + Z_MCNT);

  u16*      xin   = (u16*)     alloc((size_t)MPAD*128*2);
  u16*      xb    = (u16*)     alloc((size_t)MPAD*256*2);
  u16*      xc    = (u16*)     alloc((size_t)MPAD*256*2);
  u16*      xw    = (u16*)     alloc((size_t)MPAD*256*2);
  u16*      hgat  = (u16*)     alloc((size_t)MPAD*256*2);
  u16*      xm    = (u16*)     alloc((size_t)MPAD*256*2);

  const int* esrc = eidx;
  const int* edst = eidx + NEDGES;

  // merged setup (zeroall | convw | convxin | biascat | qk | detmask)
  setup1<<<dim3(S5), dim3(256), 0, stream>>>(
      zar, ZTOT, pmax,
      nodeW, nqmW, t0W, t1W, gatW, c0W, c1W, arena,
      x_, xin,
      t1B, t0B, c1B, c0B, tb, cb,
      qemb, qinW, qinB, nqmB, qb,
      (const unsigned char*)mraw, mcnt);
  // merged maskmat + hist
  mh<<<dim3(NBLK + (NEDGES+255)/256), dim3(256), 0, stream>>>(mraw, mcnt, mask, edst, count);
  bsum   <<<dim3(NBLK), dim3(256), 0, stream>>>(count, bsums);
  bscan  <<<dim3(1), dim3(256), 0, stream>>>(bsums, bpre);
  scanblk<<<dim3(NBLK), dim3(256), 0, stream>>>(count, bpre, offs, cursor);
  scatter<<<dim3((NEDGES+255)/256), dim3(256), 0, stream>>>(esrc, edst, cursor, ssrc);

  // x = relu(x_ @ node_in_W^T + b)
  g_nin<<<dim3(MTILES*2), dim3(256), 0, stream>>>(xin, arena+OFF_NODEW, nodeB, xb);

  for (int l = 0; l < 2; ++l) {
    float* avs_l = av + l*2*MPAD;
    float* avd_l = avs_l + MPAD;
    float* sumsC = l ? sumsC1 : sumsC0;
    float* sumsG = l ? sumsG1 : sumsG0;
    fuse3<<<dim3(MPAD/64), dim3(256), 0, stream>>>(
        l ? xm : xb, l ? wtn : (arena+OFF_NQM), l ? qbt : qb,
        arena+OFF_TCAT + l*131072, tb + l*512,
        arena+OFF_GAT + l*65536,
        gatAs + l*256, gatAd + l*256, mask, xc, xw, avs_l, avd_l);
    agg<<<dim3(12500), dim3(256), 0, stream>>>(offs, ssrc, avs_l, avd_l, xw, gatB + l*256, hgat);
    colstats<<<dim3(1024), dim3(256), 0, stream>>>(hgat, sumsC);
    foldw   <<<dim3(512), dim3(256), 0, stream>>>(arena+OFF_CCAT + l*262144, cb + l*512,
                                                  sumsC, cgnW + l*256, cgnB + l*256, cgnA + l*256, 512, wtc, btc);
    g_ccat<<<dim3(MTILES*4), dim3(256), 0, stream>>>(hgat, xc, wtc, btc, xm, mask, sumsG);
    if (l == 0)
      foldw<<<dim3(256), dim3(256), 0, stream>>>(arena+OFF_NQM + 65536, qb + 256,
                                                 sumsG, gnW, gnB, gnA, 256, wtn, qbt);
  }

  pool  <<<dim3(512), dim3(256), 0, stream>>>(xm, mask, sumsG1, gnW + 256, gnB + 256, gnA + 256, psum, pmax, pcnt);
  finalk<<<dim3(1), dim3(256), 0, stream>>>(psum, pmax, pcnt, finW, finB, outp);
}

// Round 12
// 529.409 us; speedup vs baseline: 1.2291x; 1.2291x over previous
//
#include <hip/hip_runtime.h>
#include <stdint.h>

#define NNODES 50000
#define NEDGES 400000
#define MPAD   50048   // 391 * 128
#define MTILES 391
#define ZRF    0.8f
#define GNEPS  1e-5f
#define NBLK   196     // ceil(NNODES/256)

typedef unsigned short u16;
typedef __bf16 bf16x8 __attribute__((ext_vector_type(8)));
typedef float  f32x4  __attribute__((ext_vector_type(4)));

// bf16 weight arena offsets (elements)
#define OFF_NODEW 0
#define OFF_NQM   32768
#define OFF_TCAT  163840
#define OFF_GAT   425984
#define OFF_CCAT  557056
#define W_TOTAL   1081344

__device__ __forceinline__ float b2f(u16 u){ union{uint32_t i; float f;} x; x.i=((uint32_t)u)<<16; return x.f; }
__device__ __forceinline__ u16 f2b(float f){ union{float f; uint32_t i;} x; x.f=f; uint32_t r=x.i+0x7FFFu+((x.i>>16)&1u); return (u16)(r>>16); }
__device__ __forceinline__ float lrelu(float x){ return x>0.f? x : 0.2f*x; }
__device__ __forceinline__ void atomicMaxF(float* a, float v){
  if (v>=0.f) atomicMax((int*)a, __float_as_int(v));
  else atomicMin((unsigned int*)a, (unsigned int)__float_as_int(v));
}

__device__ __forceinline__ void gl16(const void* g, void* l){
  __builtin_amdgcn_global_load_lds((const __attribute__((address_space(1))) void*)g,
                                   (__attribute__((address_space(3))) void*)l, 16, 0, 0);
}
__device__ __forceinline__ void bar(){
  __builtin_amdgcn_sched_barrier(0);
  asm volatile("" ::: "memory");
  __builtin_amdgcn_s_barrier();
  asm volatile("" ::: "memory");
  __builtin_amdgcn_sched_barrier(0);
}

// ---------------- bf16 MFMA GEMM body ----------------
// DUAL=0: out[M, NT*128] = op(A @ B^T + bias), 128x128 tile. DOTAV=1: fused avs/avd dot epilogue.
// DUAL=1: 128x64 tile; B halves rows [bn,bn+64) and [256+bn,...); relu opt; mix by mask.
// STATS=1: masked per-column sum/sumsq atomics (on mixed value).
// BK=32, async global_load_lds staging (pre-swizzled source, linear LDS, swizzled read),
// TRIPLE-buffered 2-deep prefetch: one barrier per K-tile, counted vmcnt(4), XCD-chunked N-inner.
template<int DUAL,int SPLIT,int RELU,int STATS,int DOTAV>
__device__ __forceinline__ void gemm_body(const u16* __restrict__ A0, const u16* __restrict__ A1,
    int ldA, const u16* __restrict__ B, const float* __restrict__ bias,
    u16* __restrict__ out, int ldo, int NT, int K,
    const uint32_t* __restrict__ mask, float* __restrict__ sums,
    const float* __restrict__ asrc, const float* __restrict__ adst,
    float* __restrict__ avs, float* __restrict__ avd)
{
  __shared__ alignas(16) char smem[50176];   // 3 x 16KB staging + 1KB was/val
  char* sm = smem;
  float* was = (float*)(smem + 49152);
  float* val = was + 128;

  const int tid  = threadIdx.x;
  const int nwg = gridDim.x;
  const int qc = nwg >> 3, rc = nwg & 7;
  const int xcd = blockIdx.x & 7, xi = blockIdx.x >> 3;
  const int lt = (xcd < rc ? xcd * (qc + 1) : rc * (qc + 1) + (xcd - rc) * qc) + xi;
  const int bm0 = (lt / NT) * 128;
  const int bn0 = (lt % NT) * (DUAL ? 64 : 128);

  if (DUAL && tid < 128) {
    int gr = bm0 + tid;
    int mk = (gr < NNODES) ? (mask[gr] != 0) : 0;
    was[tid] = mk ? ZRF : (1.0f - ZRF);
    val[tid] = (gr < NNODES) ? 1.0f : 0.0f;
  }

  const int lane = tid & 63;
  const int wv   = tid >> 6;
  const int wm   = (wv >> 1) * 64;
  const int wn   = (wv & 1) * (DUAL ? 32 : 64);
  const int lrow = lane & 15;
  const int kg16 = (lane >> 4) * 16;          // k-granule byte offset within 64B row
  const int swz  = ((lrow >> 1) & 3) << 4;    // read-side XOR swizzle

  // staging geometry: each thread issues 4 x 16B gload_lds per K-tile
  const int rA  = ((wv << 6) + lane) >> 2;    // staged row (issue0); issue1 = +64
  const int gsw = (((lane & 3) ^ ((rA >> 1) & 3)) << 3);  // pre-swizzled source granule (elements)
  const u16* pa  = A0 + (size_t)(bm0 + rA) * ldA + gsw;
  const u16* pa2 = pa + 64 * ldA;
  const u16* pa1  = SPLIT ? (A1 + (size_t)(bm0 + rA) * 256 + gsw) : nullptr;
  const u16* pa12 = SPLIT ? (pa1 + 64 * 256) : nullptr;
  const u16* pb0 = B + (size_t)(bn0 + rA) * K + gsw;
  const u16* pb1 = DUAL ? (B + (size_t)(256 + bn0 + rA) * K + gsw) : (pb0 + (size_t)64 * K);
  const int dA0 = wv * 1024, dA1 = 4096 + wv * 1024;
  const int dB0 = 8192 + wv * 1024, dB1 = 12288 + wv * 1024;

  const int KT = K >> 5;
  f32x4 acc[DUAL ? 2 : 1][4][DUAL ? 2 : 4] = {};

#define STAGE(off, ktv) do { \
    int ks_ = (ktv) * 32; \
    const u16 *qa_, *qa2_; \
    if (SPLIT && ks_ >= 256) { qa_ = pa1 + (ks_ - 256); qa2_ = pa12 + (ks_ - 256); } \
    else                     { qa_ = pa + ks_;           qa2_ = pa2 + ks_; } \
    char* db_ = sm + (off); \
    gl16(qa_,       db_ + dA0); \
    gl16(qa2_,      db_ + dA1); \
    gl16(pb0 + ks_, db_ + dB0); \
    gl16(pb1 + ks_, db_ + dB1); \
  } while (0)

  STAGE(0, 0);
  if (KT > 1) STAGE(16384, 1);
  int rd = 0;
  for (int kt = 0; kt < KT; ++kt) {
    if (kt + 1 < KT) { asm volatile("s_waitcnt vmcnt(4)" ::: "memory"); }
    else             { asm volatile("s_waitcnt vmcnt(0)" ::: "memory"); }
    bar();                                     // buf rd ready; all waves done with buf (rd+2)%3
    if (kt + 2 < KT) { int st = rd >= 1 ? rd - 1 : 2; STAGE(st * 16384, kt + 2); }
    const char* Ab = sm + rd * 16384;
    const char* Bb = Ab + 8192;
    bf16x8 af[4];
#pragma unroll
    for (int mi = 0; mi < 4; ++mi)
      af[mi] = *(const bf16x8*)(Ab + (wm + mi * 16 + lrow) * 64 + (kg16 ^ swz));
    if (DUAL) {
#pragma unroll
      for (int ni = 0; ni < 2; ++ni) {
        int ro = (wn + ni * 16 + lrow) * 64 + (kg16 ^ swz);
        bf16x8 b0 = *(const bf16x8*)(Bb + ro);
        bf16x8 b1 = *(const bf16x8*)(Bb + 4096 + ro);
#pragma unroll
        for (int mi = 0; mi < 4; ++mi) {
          acc[0][mi][ni] = __builtin_amdgcn_mfma_f32_16x16x32_bf16(af[mi], b0, acc[0][mi][ni], 0, 0, 0);
          acc[DUAL?1:0][mi][ni] = __builtin_amdgcn_mfma_f32_16x16x32_bf16(af[mi], b1, acc[DUAL?1:0][mi][ni], 0, 0, 0);
        }
      }
    } else {
#pragma unroll
      for (int ni = 0; ni < (DUAL ? 2 : 4); ++ni) {
        bf16x8 bv = *(const bf16x8*)(Bb + (wn + ni * 16 + lrow) * 64 + (kg16 ^ swz));
#pragma unroll
        for (int mi = 0; mi < 4; ++mi)
          acc[0][mi][ni] = __builtin_amdgcn_mfma_f32_16x16x32_bf16(af[mi], bv, acc[0][mi][ni], 0, 0, 0);
      }
    }
    rd = (rd + 1 == 3) ? 0 : rd + 1;
  }
#undef STAGE
  bar();   // all waves done reading staging buffers before epilogue overwrites

  // ---- epilogue: LDS transpose -> coalesced stores ----
  const int rb = (lane >> 4) * 4;   // D: col = lane&15, row = (lane>>4)*4 + reg
  u16* ep = (u16*)smem;
  if (DUAL) {
    float sA[2] = {0, 0}, qA[2] = {0, 0};
#pragma unroll
    for (int ni = 0; ni < 2; ++ni) {
      int coll = wn + ni * 16 + lrow;
      float b1v = bias[bn0 + coll];
      float b0v = bias[256 + bn0 + coll];
#pragma unroll
      for (int mi = 0; mi < 4; ++mi) {
        int rowl = wm + mi * 16 + rb;
#pragma unroll
        for (int r = 0; r < 4; ++r) {
          float v1 = acc[0][mi][ni][r] + b1v;
          float v0 = acc[DUAL?1:0][mi][ni][r] + b0v;
          if (RELU) { v1 = fmaxf(v1, 0.f); v0 = fmaxf(v0, 0.f); }
          float wa = was[rowl + r];
          float v = wa * v1 + (1.0f - wa) * v0;
          if (STATS) { float vl = val[rowl + r]; sA[ni] += v * vl; qA[ni] += v * v * vl; }
          ep[(rowl + r) * 72 + coll] = f2b(v);
        }
      }
    }
    bar();
#pragma unroll
    for (int p = 0; p < 4; ++p) {
      int rowl = p * 32 + (tid >> 3);
      uint4 v = *(const uint4*)&ep[rowl * 72 + (tid & 7) * 8];
      *(uint4*)&out[(size_t)(bm0 + rowl) * ldo + bn0 + (tid & 7) * 8] = v;
    }
    if (STATS) {
#pragma unroll
      for (int ni = 0; ni < 2; ++ni) {
        sA[ni] += __shfl_xor(sA[ni], 16); sA[ni] += __shfl_xor(sA[ni], 32);
        qA[ni] += __shfl_xor(qA[ni], 16); qA[ni] += __shfl_xor(qA[ni], 32);
      }
      if (lane < 16) {
#pragma unroll
        for (int ni = 0; ni < 2; ++ni) {
          int gc = bn0 + wn + ni * 16 + lane;
          atomicAdd(&sums[gc], sA[ni]);
          atomicAdd(&sums[256 + gc], qA[ni]);
        }
      }
    }
  } else {
    float sp[4][4] = {}, dp[4][4] = {};
#pragma unroll
    for (int ni = 0; ni < 4; ++ni) {
      int coll = wn + ni * 16 + lrow;
      float bv = bias ? bias[bn0 + coll] : 0.f;
      float as_ = 0.f, ad_ = 0.f;
      if (DOTAV) { as_ = asrc[bn0 + coll]; ad_ = adst[bn0 + coll]; }
#pragma unroll
      for (int mi = 0; mi < 4; ++mi) {
        int rowl = wm + mi * 16 + rb;
#pragma unroll
        for (int r = 0; r < 4; ++r) {
          float v = acc[0][mi][ni][r] + bv;
          if (RELU) v = fmaxf(v, 0.f);
          if (DOTAV) { sp[mi][r] += v * as_; dp[mi][r] += v * ad_; }
          ep[(rowl + r) * 132 + coll] = f2b(v);
        }
      }
    }
    bar();
#pragma unroll
    for (int p = 0; p < 8; ++p) {
      int rowl = p * 16 + (tid >> 4);
      uint4 v = *(const uint4*)&ep[rowl * 132 + (tid & 15) * 8];
      *(uint4*)&out[(size_t)(bm0 + rowl) * ldo + bn0 + (tid & 15) * 8] = v;
    }
    if (DOTAV) {
#pragma unroll
      for (int mi = 0; mi < 4; ++mi)
#pragma unroll
        for (int r = 0; r < 4; ++r) {
          float s_ = sp[mi][r], d_ = dp[mi][r];
          s_ += __shfl_xor(s_, 1); s_ += __shfl_xor(s_, 2); s_ += __shfl_xor(s_, 4); s_ += __shfl_xor(s_, 8);
          d_ += __shfl_xor(d_, 1); d_ += __shfl_xor(d_, 2); d_ += __shfl_xor(d_, 4); d_ += __shfl_xor(d_, 8);
          if (lrow == 0) {
            int row = bm0 + wm + mi * 16 + (lane >> 4) * 4 + r;
            atomicAdd(&avs[row], s_);
            atomicAdd(&avd[row], d_);
          }
        }
    }
  }
}

// named wrappers for rocprof attribution
__global__ __launch_bounds__(256, 3) void g_nin(const u16* __restrict__ A, const u16* __restrict__ W,
    const float* __restrict__ b, u16* __restrict__ o)
{ gemm_body<0,0,1,0,0>(A, nullptr, 128, W, b, o, 256, 2, 128, nullptr, nullptr, nullptr, nullptr, nullptr, nullptr); }

__global__ __launch_bounds__(256, 3) void g_nqm(const u16* __restrict__ A, const u16* __restrict__ W,
    const float* __restrict__ b, u16* __restrict__ o)
{ gemm_body<0,0,1,0,0>(A, nullptr, 256, W, b, o, 256, 2, 256, nullptr, nullptr, nullptr, nullptr, nullptr, nullptr); }

__global__ __launch_bounds__(256, 3) void g_gat(const u16* __restrict__ A, const u16* __restrict__ W,
    u16* __restrict__ o, const float* __restrict__ asrc, const float* __restrict__ adst,
    float* __restrict__ avs, float* __restrict__ avd)
{ gemm_body<0,0,0,0,1>(A, nullptr, 256, W, nullptr, o, 256, 2, 256, nullptr, nullptr, asrc, adst, avs, avd); }

__global__ __launch_bounds__(256, 3) void g_tcat(const u16* __restrict__ A, const u16* __restrict__ W,
    const float* __restrict__ b, u16* __restrict__ o, const uint32_t* __restrict__ mask)
{ gemm_body<1,0,1,0,0>(A, nullptr, 256, W, b, o, 256, 4, 256, mask, nullptr, nullptr, nullptr, nullptr, nullptr); }

__global__ __launch_bounds__(256, 3) void g_ccat(const u16* __restrict__ A0, const u16* __restrict__ A1,
    const u16* __restrict__ W, const float* __restrict__ b, u16* __restrict__ o,
    const uint32_t* __restrict__ mask, float* __restrict__ sums)
{ gemm_body<1,1,0,1,0>(A0, A1, 256, W, b, o, 256, 4, 512, mask, sums, nullptr, nullptr, nullptr, nullptr); }

// ---------------- weight fold with inline graph-norm scale/shift ----------------
__global__ void foldw(const u16* __restrict__ Ws, const float* __restrict__ bs,
                      const float* __restrict__ sums, const float* __restrict__ w,
                      const float* __restrict__ b, const float* __restrict__ a,
                      int K, u16* __restrict__ Wd, float* __restrict__ bd){
  __shared__ float scs[256], shs[256];
  int n = blockIdx.x, t = threadIdx.x;
  {
    const float invn = 1.0f / (float)NNODES;
    float mu  = sums[t] * invn;
    float ex2 = sums[256 + t] * invn;
    float av  = a[t];
    float var = ex2 - (2.0f*av - av*av)*mu*mu;
    float sc  = w[t] / sqrtf(var + GNEPS);
    scs[t] = sc;
    shs[t] = b[t] - sc*av*mu;
  }
  __syncthreads();
  float bacc = 0.f;
  for (int k = t; k < K; k += 256) {
    float wv = b2f(Ws[(size_t)n * K + k]);
    if (k < 256) { bacc += wv * shs[k]; wv *= scs[k]; }
    Wd[(size_t)n * K + k] = f2b(wv);
  }
  for (int d = 32; d; d >>= 1) bacc += __shfl_xor(bacc, d);
  __shared__ float red[4];
  if ((t & 63) == 0) red[t >> 6] = bacc;
  __syncthreads();
  if (t == 0) bd[n] = bs[n] + red[0] + red[1] + red[2] + red[3];
}

// ---------------- merged setup kernel: zeroall | convw | convxin | biascat | qk | detmask ----------------
#define S0 256
#define S1 (S0 + 4224)
#define S2 (S1 + 6256)
#define S3 (S2 + 8)
#define S4 (S3 + 1)
#define S5 (S4 + NBLK)
__global__ void setup1(
    float* __restrict__ zar, int ztot, float* __restrict__ pmax,
    const float* __restrict__ nodeW, const float* __restrict__ nqmW,
    const float* __restrict__ t0W, const float* __restrict__ t1W,
    const float* __restrict__ gatW, const float* __restrict__ c0W,
    const float* __restrict__ c1W, u16* __restrict__ arena,
    const float* __restrict__ x, u16* __restrict__ xin,
    const float* __restrict__ t1b, const float* __restrict__ t0b,
    const float* __restrict__ c1b, const float* __restrict__ c0b,
    float* __restrict__ tb, float* __restrict__ cb,
    const float* __restrict__ qemb, const float* __restrict__ qinW,
    const float* __restrict__ qinB, const float* __restrict__ nqmB,
    float* __restrict__ qb,
    const unsigned char* __restrict__ mb, int* __restrict__ mcnt)
{
  int b = blockIdx.x, t = threadIdx.x;
  if (b < S0) {
    int i = b*256 + t;
    if (i < 256) pmax[i] = -__builtin_inff();
    for (int j = i; j < ztot; j += S0*256) zar[j] = 0.f;
  } else if (b < S1) {
    int idx = (b - S0)*256 + t;
    if (idx >= W_TOTAL) return;
    float v;
    if (idx < OFF_NQM) { v = nodeW[idx]; }
    else if (idx < OFF_TCAT){ int i = idx - OFF_NQM;  int l=i>>16; int r=(i>>8)&255; int k=i&255; v = nqmW[l*131072 + r*512 + k]; }
    else if (idx < OFF_GAT) { int i = idx - OFF_TCAT; int l=i>>17; int n=(i>>8)&511; int k=i&255;
                              const float* s = (n<256)? t1W : t0W; v = s[l*65536 + (n&255)*256 + k]; }
    else if (idx < OFF_CCAT){ int i = idx - OFF_GAT;  v = gatW[i]; }
    else                    { int i = idx - OFF_CCAT; int l=i>>18; int n=(i>>9)&511; int k=i&511;
                              const float* s = (n<256)? c1W : c0W; v = s[l*131072 + (n&255)*512 + k]; }
    arena[idx] = f2b(v);
  } else if (b < S2) {
    int idx = (b - S1)*256 + t;
    if (idx >= MPAD*32) return;
    int n = idx >> 5; int c = (idx & 31)*4;
    float4 v = make_float4(0.f,0.f,0.f,0.f);
    if (n < NNODES) v = *(const float4*)&x[(size_t)n*128 + c];
    ushort4 r; r.x=f2b(v.x); r.y=f2b(v.y); r.z=f2b(v.z); r.w=f2b(v.w);
    *(ushort4*)&xin[(size_t)n*128 + c] = r;
  } else if (b < S3) {
    int i = (b - S2)*256 + t;
    if (i >= 2048) return;
    int which = i >> 10; int j = i & 1023; int l = j >> 9; int n = j & 511;
    const float* b1 = which ? c1b : t1b;
    const float* b0 = which ? c0b : t0b;
    float v = (n < 256) ? b1[l*256 + n] : b0[l*256 + n - 256];
    (which ? cb : tb)[l*512 + n] = v;
  } else if (b < S4) {
    __shared__ float qvs[256];
    float a = qinB[t];
    for (int d = 0; d < 128; ++d) a += qemb[d] * qinW[t*128 + d];
    qvs[t] = fmaxf(a, 0.f);
    __syncthreads();
    for (int l = 0; l < 2; ++l) {
      const float* wr = nqmW + l*131072 + t*512 + 256;
      float acc = nqmB[l*256 + t];
      for (int j = 0; j < 256; ++j) acc += wr[j] * qvs[j];
      qb[l*256 + t] = acc;
    }
  } else {
    int i = (b - S4)*256 + t;
    int c = (i < NNODES) ? (mb[i] != 0) : 0;
    for (int d = 32; d; d >>= 1) c += __shfl_xor(c, d);
    __shared__ int red[4];
    if ((t & 63) == 0) red[t >> 6] = c;
    __syncthreads();
    if (t == 0) atomicAdd(mcnt, red[0] + red[1] + red[2] + red[3]);
  }
}

// ---------------- merged maskmat + hist ----------------
__global__ void mh(const void* __restrict__ mraw, const int* __restrict__ mcnt,
                   uint32_t* __restrict__ mask,
                   const int* __restrict__ dst, int* __restrict__ count){
  int b = blockIdx.x, t = threadIdx.x;
  if (b < NBLK) {
    int i = b*256 + t;
    if (i >= NNODES) return;
    int f = ((*mcnt) * 8 > NNODES * 3);
    mask[i] = f ? (((const unsigned char*)mraw)[i] != 0) : (((const int*)mraw)[i] != 0);
  } else {
    int i = (b - NBLK)*256 + t;
    if (i < NEDGES) atomicAdd(&count[dst[i]], 1);
  }
}

// ---------------- scan chain ----------------
__global__ void bsum(const int* __restrict__ count, int* __restrict__ bsums){
  int b = blockIdx.x, t = threadIdx.x;
  int i = b * 256 + t;
  int v = (i < NNODES) ? count[i] : 0;
  for (int d = 32; d; d >>= 1) v += __shfl_xor(v, d);
  __shared__ int red[4];
  if ((t & 63) == 0) red[t >> 6] = v;
  __syncthreads();
  if (t == 0) bsums[b] = red[0] + red[1] + red[2] + red[3];
}

__global__ void bscan(const int* __restrict__ bsums, int* __restrict__ bpre){
  int t = threadIdx.x;
  int v = (t < NBLK) ? bsums[t] : 0;
  __shared__ int tmp[256];
  tmp[t] = v;
  __syncthreads();
  for (int d = 1; d < 256; d <<= 1) {
    int add = (t >= d) ? tmp[t - d] : 0;
    __syncthreads();
    tmp[t] += add;
    __syncthreads();
  }
  if (t < NBLK) bpre[t] = tmp[t] - v;
}

__global__ void scanblk(const int* __restrict__ count, const int* __restrict__ bpre,
                        int* __restrict__ offs, int* __restrict__ cursor){
  int b = blockIdx.x, t = threadIdx.x;
  int i = b * 256 + t;
  int v = (i < NNODES) ? count[i] : 0;
  __shared__ int tmp[256];
  tmp[t] = v;
  __syncthreads();
  for (int d = 1; d < 256; d <<= 1) {
    int add = (t >= d) ? tmp[t - d] : 0;
    __syncthreads();
    tmp[t] += add;
    __syncthreads();
  }
  int excl = bpre[b] + tmp[t] - v;
  if (i < NNODES) { offs[i] = excl; cursor[i] = excl; }
  if (i == NNODES - 1) offs[NNODES] = excl + v;
}

__global__ void scatter(const int* __restrict__ src, const int* __restrict__ dst,
                        int* __restrict__ cursor, int* __restrict__ ssrc){
  int i = blockIdx.x*256 + threadIdx.x;
  if (i >= NEDGES) return;
  int p = atomicAdd(&cursor[dst[i]], 1);
  ssrc[p] = src[i];
}

// ---------------- graph kernels ----------------
// one wave per node: softmax over incoming edges (+self loop), gather-accumulate xw rows.
// fast path: deg<=64 -> per-lane logit in register, 8-way unrolled gather via shfl broadcast.
__global__ void agg(const int* __restrict__ offs, const int* __restrict__ ssrc,
                    const float* __restrict__ avs, const float* __restrict__ avd,
                    const u16* __restrict__ xw, const float* __restrict__ gbias,
                    u16* __restrict__ out){
  int v = (blockIdx.x*256 + threadIdx.x) >> 6;
  int lane = threadIdx.x & 63;
  if (v >= NNODES) return;
  int o0 = offs[v], o1 = offs[v+1];
  int deg = o1 - o0;
  float ad = avd[v];
  float slog = lrelu(avs[v] + ad);
  int c = lane*4;
  ushort4 xv = *(const ushort4*)&xw[(size_t)v*256 + c];
  float a0, a1, a2, a3;
  if (deg <= 64) {
    int s = 0; float logit = -3.0e38f;
    if (lane < deg) { s = ssrc[o0 + lane]; logit = lrelu(avs[s] + ad); }
    float m = fmaxf(slog, logit);
    for (int d = 32; d; d >>= 1) m = fmaxf(m, __shfl_xor(m, d));
    float w = (lane < deg) ? __expf(logit - m) : 0.f;
    float den = w + ((lane == 0) ? __expf(slog - m) : 0.f);
    for (int d = 32; d; d >>= 1) den += __shfl_xor(den, d);
    float rden = 1.0f / (den + 1e-16f);
    w *= rden;
    float wgt = __expf(slog - m) * rden;
    a0 = wgt*b2f(xv.x); a1 = wgt*b2f(xv.y); a2 = wgt*b2f(xv.z); a3 = wgt*b2f(xv.w);
    int i = 0;
    for (; i + 8 <= deg; i += 8) {
      ushort4 q[8]; float ww[8];
#pragma unroll
      for (int j = 0; j < 8; ++j) {
        int sj = __shfl(s, i + j); ww[j] = __shfl(w, i + j);
        q[j] = *(const ushort4*)&xw[(size_t)sj*256 + c];
      }
#pragma unroll
      for (int j = 0; j < 8; ++j) {
        a0 += ww[j]*b2f(q[j].x); a1 += ww[j]*b2f(q[j].y);
        a2 += ww[j]*b2f(q[j].z); a3 += ww[j]*b2f(q[j].w);
      }
    }
    for (; i + 4 <= deg; i += 4) {
      ushort4 q[4]; float ww[4];
#pragma unroll
      for (int j = 0; j < 4; ++j) {
        int sj = __shfl(s, i + j); ww[j] = __shfl(w, i + j);
        q[j] = *(const ushort4*)&xw[(size_t)sj*256 + c];
      }
#pragma unroll
      for (int j = 0; j < 4; ++j) {
        a0 += ww[j]*b2f(q[j].x); a1 += ww[j]*b2f(q[j].y);
        a2 += ww[j]*b2f(q[j].z); a3 += ww[j]*b2f(q[j].w);
      }
    }
    for (; i < deg; ++i) {
      int si = __shfl(s, i); float wi = __shfl(w, i);
      ushort4 q = *(const ushort4*)&xw[(size_t)si*256 + c];
      a0 += wi*b2f(q.x); a1 += wi*b2f(q.y); a2 += wi*b2f(q.z); a3 += wi*b2f(q.w);
    }
  } else {
    float m = slog;
    for (int i = o0 + lane; i < o1; i += 64) m = fmaxf(m, lrelu(avs[ssrc[i]] + ad));
    for (int d = 32; d; d >>= 1) m = fmaxf(m, __shfl_xor(m, d));
    float den = (lane == 0) ? __expf(slog - m) : 0.f;
    for (int i = o0 + lane; i < o1; i += 64) den += __expf(lrelu(avs[ssrc[i]] + ad) - m);
    for (int d = 32; d; d >>= 1) den += __shfl_xor(den, d);
    float rden = 1.0f / (den + 1e-16f);
    float wgt = __expf(slog - m) * rden;
    a0 = wgt*b2f(xv.x); a1 = wgt*b2f(xv.y); a2 = wgt*b2f(xv.z); a3 = wgt*b2f(xv.w);
    for (int i = o0; i < o1; ++i) {
      int si = ssrc[i];
      float wi = __expf(lrelu(avs[si] + ad) - m) * rden;
      ushort4 q = *(const ushort4*)&xw[(size_t)si*256 + c];
      a0 += wi*b2f(q.x); a1 += wi*b2f(q.y); a2 += wi*b2f(q.z); a3 += wi*b2f(q.w);
    }
  }
  float4 bb = *(const float4*)&gbias[c];
  ushort4 r;
  r.x = f2b(a0 + bb.x); r.y = f2b(a1 + bb.y); r.z = f2b(a2 + bb.z); r.w = f2b(a3 + bb.w);
  *(ushort4*)&out[(size_t)v*256 + c] = r;
}

__global__ void colstats(const u16* __restrict__ x, float* __restrict__ sums){
  int c = threadIdx.x;
  float s = 0.f, q = 0.f;
  for (int n = blockIdx.x; n < NNODES; n += gridDim.x){
    float v = b2f(x[(size_t)n*256 + c]); s += v; q += v*v;
  }
  atomicAdd(&sums[c], s); atomicAdd(&sums[256 + c], q);
}

// pool over affine(x) with inline graph-norm scale/shift from sums
__global__ void pool(const u16* __restrict__ x, const uint32_t* __restrict__ mask,
                     const float* __restrict__ sums, const float* __restrict__ w,
                     const float* __restrict__ b, const float* __restrict__ a,
                     float* __restrict__ psum, float* __restrict__ pmax, int* __restrict__ pcnt){
  int c = threadIdx.x;
  const float invn = 1.0f / (float)NNODES;
  float mu  = sums[c] * invn;
  float ex2 = sums[256 + c] * invn;
  float av  = a[c];
  float var = ex2 - (2.0f*av - av*av)*mu*mu;
  float sc  = w[c] / sqrtf(var + GNEPS);
  float sh  = b[c] - sc*av*mu;
  float s = 0.f, mx = -__builtin_inff(); int cnt = 0;
  for (int n = blockIdx.x; n < NNODES; n += gridDim.x){
    if (mask[n]){
      float v = b2f(x[(size_t)n*256 + c]) * sc + sh;
      s += v; mx = fmaxf(mx, v); cnt++;
    }
  }
  atomicAdd(&psum[c], s);
  atomicMaxF(&pmax[c], mx);
  if (c == 0) atomicAdd(pcnt, cnt);
}

__global__ void finalk(const float* __restrict__ psum, const float* __restrict__ pmax,
                       const int* __restrict__ pcnt, const float* __restrict__ W,
                       const float* __restrict__ b, float* __restrict__ out){
  int o = threadIdx.x;
  float cnt = fmaxf((float)(*pcnt), 1.0f);
  float inv = 1.0f / cnt;
  const float* wr = W + o*768;
  float acc = b[o];
  for (int j = 0; j < 256; ++j) acc += (psum[j]*inv) * wr[j];
  for (int j = 0; j < 256; ++j) acc += pmax[j] * wr[256 + j];
  for (int j = 0; j < 256; ++j) acc += psum[j] * wr[512 + j];
  out[o] = acc;
}

// ---------------- host orchestration ----------------
extern "C" void kernel_launch(void* const* d_in, const int* in_sizes, int n_in,
                              void* d_out, int out_size, void* d_ws, size_t ws_size,
                              hipStream_t stream)
{
  (void)in_sizes; (void)n_in; (void)out_size; (void)ws_size;
  const float* x_    = (const float*)d_in[0];
  const int*   eidx  = (const int*)  d_in[1];
  const float* qemb  = (const float*)d_in[3];
  const void*  mraw  =               d_in[4];
  const float* nodeW = (const float*)d_in[5];
  const float* nodeB = (const float*)d_in[6];
  const float* qinW  = (const float*)d_in[9];
  const float* qinB  = (const float*)d_in[10];
  const float* nqmW  = (const float*)d_in[11];
  const float* nqmB  = (const float*)d_in[12];
  const float* t0W   = (const float*)d_in[15];
  const float* t0B   = (const float*)d_in[16];
  const float* t1W   = (const float*)d_in[17];
  const float* t1B   = (const float*)d_in[18];
  const float* gatW  = (const float*)d_in[19];
  const float* gatAs = (const float*)d_in[20];
  const float* gatAd = (const float*)d_in[21];
  const float* gatB  = (const float*)d_in[22];
  const float* cgnW  = (const float*)d_in[23];
  const float* cgnB  = (const float*)d_in[24];
  const float* cgnA  = (const float*)d_in[25];
  const float* c0W   = (const float*)d_in[26];
  const float* c0B   = (const float*)d_in[27];
  const float* c1W   = (const float*)d_in[28];
  const float* c1B   = (const float*)d_in[29];
  const float* gnW   = (const float*)d_in[30];
  const float* gnB   = (const float*)d_in[31];
  const float* gnA   = (const float*)d_in[32];
  const float* finW  = (const float*)d_in[33];
  const float* finB  = (const float*)d_in[34];
  float* outp = (float*)d_out;

  char* p = (char*)d_ws;
  auto alloc = [&](size_t b)->char*{ char* r = p; p += (b + 511) & ~(size_t)511; return r; };
  u16*      arena = (u16*)     alloc((size_t)W_TOTAL*2);
  u16*      wtc   = (u16*)     alloc((size_t)512*512*2);
  u16*      wtn   = (u16*)     alloc((size_t)256*256*2);
  float*    btc   = (float*)   alloc(512*4);
  float*    qbt   = (float*)   alloc(256*4);
  float*    tb    = (float*)   alloc(1024*4);
  float*    cb    = (float*)   alloc(1024*4);
  float*    qb    = (float*)   alloc(512*4);
  float*    pmax  = (float*)   alloc(256*4);
  uint32_t* mask  = (uint32_t*)alloc((size_t)NNODES*4);
  int*      offs  = (int*)     alloc((size_t)(NNODES+1)*4);
  int*      cursor= (int*)     alloc((size_t)NNODES*4);
  int*      ssrc  = (int*)     alloc((size_t)NEDGES*4);
  int*      bsums = (int*)     alloc((size_t)NBLK*4);
  int*      bpre  = (int*)     alloc((size_t)NBLK*4);

  // zero arena: count | sumsC0 sumsC1 sumsG0 sumsG1 | av(4*MPAD) | psum | pcnt | mcnt
  const int Z_SUMS  = 50048;
  const int Z_AV    = Z_SUMS + 2048;
  const int Z_PSUM  = Z_AV + 4*MPAD;
  const int Z_PCNT  = Z_PSUM + 256;
  const int Z_MCNT  = Z_PCNT + 64;
  const int ZTOT    = Z_MCNT + 64;
  float*    zar   = (float*)   alloc((size_t)ZTOT*4);
  int*      count = (int*)zar;
  float*    sumsC0= zar + Z_SUMS;
  float*    sumsC1= zar + Z_SUMS + 512;
  float*    sumsG0= zar + Z_SUMS + 1024;
  float*    sumsG1= zar + Z_SUMS + 1536;
  float*    av    = zar + Z_AV;      // [avs0|avd0|avs1|avd1], MPAD each
  float*    psum  = zar + Z_PSUM;
  int*      pcnt  = (int*)(zar + Z_PCNT);
  int*      mcnt  = (int*)(zar + Z_MCNT);

  u16*      xin   = (u16*)     alloc((size_t)MPAD*128*2);
  u16*      xb    = (u16*)     alloc((size_t)MPAD*256*2);
  u16*      xc    = (u16*)     alloc((size_t)MPAD*256*2);
  u16*      hb    = (u16*)     alloc((size_t)MPAD*256*2);
  u16*      xw    = (u16*)     alloc((size_t)MPAD*256*2);
  u16*      hgat  = (u16*)     alloc((size_t)MPAD*256*2);
  u16*      xm    = (u16*)     alloc((size_t)MPAD*256*2);

  const int* esrc = eidx;
  const int* edst = eidx + NEDGES;

  // merged setup (zeroall | convw | convxin | biascat | qk | detmask)
  setup1<<<dim3(S5), dim3(256), 0, stream>>>(
      zar, ZTOT, pmax,
      nodeW, nqmW, t0W, t1W, gatW, c0W, c1W, arena,
      x_, xin,
      t1B, t0B, c1B, c0B, tb, cb,
      qemb, qinW, qinB, nqmB, qb,
      (const unsigned char*)mraw, mcnt);
  // merged maskmat + hist
  mh<<<dim3(NBLK + (NEDGES+255)/256), dim3(256), 0, stream>>>(mraw, mcnt, mask, edst, count);
  bsum   <<<dim3(NBLK), dim3(256), 0, stream>>>(count, bsums);
  bscan  <<<dim3(1), dim3(256), 0, stream>>>(bsums, bpre);
  scanblk<<<dim3(NBLK), dim3(256), 0, stream>>>(count, bpre, offs, cursor);
  scatter<<<dim3((NEDGES+255)/256), dim3(256), 0, stream>>>(esrc, edst, cursor, ssrc);

  // x = relu(x_ @ node_in_W^T + b)
  g_nin<<<dim3(MTILES*2), dim3(256), 0, stream>>>(xin, arena+OFF_NODEW, nodeB, xb);

  for (int l = 0; l < 2; ++l) {
    float* avs_l = av + l*2*MPAD;
    float* avd_l = avs_l + MPAD;
    float* sumsC = l ? sumsC1 : sumsC0;
    float* sumsG = l ? sumsG1 : sumsG0;
    // xc = relu(x @ Wnqm^T + qbias)   (layer1: gn-folded weights, xm input)
    if (l == 0)
      g_nqm<<<dim3(MTILES*2), dim3(256), 0, stream>>>(xb, arena+OFF_NQM, qb, xc);
    else
      g_nqm<<<dim3(MTILES*2), dim3(256), 0, stream>>>(xm, wtn, qbt, xc);
    // h = mix(relu(xc@t1^T), relu(xc@t0^T))   [fused dual-half GEMM]
    g_tcat<<<dim3(MTILES*4), dim3(256), 0, stream>>>(xc, arena+OFF_TCAT + l*131072, tb + l*512, hb, mask);
    // xw = h @ gat_W^T  + fused avs/avd dot epilogue
    g_gat<<<dim3(MTILES*2), dim3(256), 0, stream>>>(hb, arena+OFF_GAT + l*65536, xw,
                                                    gatAs + l*256, gatAd + l*256, avs_l, avd_l);
    agg  <<<dim3(12500), dim3(256), 0, stream>>>(offs, ssrc, avs_l, avd_l, xw, gatB + l*256, hgat);
    // cgn stats -> fold into ccat weights (scale/shift computed inline in foldw)
    colstats<<<dim3(1024), dim3(256), 0, stream>>>(hgat, sumsC);
    foldw   <<<dim3(512), dim3(256), 0, stream>>>(arena+OFF_CCAT + l*262144, cb + l*512,
                                                  sumsC, cgnW + l*256, cgnB + l*256, cgnA + l*256, 512, wtc, btc);
    // xm = mix(hc@c1'^T, hc@c0'^T) + masked col stats    [fused dual-half GEMM, split A = [hgat|xc]]
    g_ccat<<<dim3(MTILES*4), dim3(256), 0, stream>>>(hgat, xc, wtc, btc, xm, mask, sumsG);
    if (l == 0)
      foldw<<<dim3(256), dim3(256), 0, stream>>>(arena+OFF_NQM + 65536, qb + 256,
                                                 sumsG, gnW, gnB, gnA, 256, wtn, qbt);
  }

  // masked pooling of affine(xm) (gn inline) + final linear
  pool  <<<dim3(512), dim3(256), 0, stream>>>(xm, mask, sumsG1, gnW + 256, gnB + 256, gnA + 256, psum, pmax, pcnt);
  finalk<<<dim3(1), dim3(256), 0, stream>>>(psum, pmax, pcnt, finW, finB, outp);
}